// Round 6
// baseline (2369.714 us; speedup 1.0000x reference)
//
#include <hip/hip_runtime.h>
#include <math.h>

#define B_   4
#define S_   2048
#define DIM_ 1024
#define NH_  8
#define DH_  128
#define CS_  16
#define NS_  128
#define NSEG 8
#define SEGC 16          // chunks per segment
#define EPSv  1e-6f
#define LNEPS 1e-5f

// workspace layout (float offsets) — total 4,698,368 floats = 18.8 MB
#define IG_OFF    0u        // (B*NH*S)
#define LF_OFF    65536u
#define LFACC_OFF 131072u
#define GEXP_OFF  196608u
#define STAB_OFF  262144u
#define DECAY_OFF 327680u
#define A_OFF     393216u   // (B*NH*NS)
#define BB_OFF    397312u
#define DP_OFF    401408u   // decay-product from segment start (exclusive), per chunk
#define DPF_OFF   405504u   // full-segment decay product, per (bh,seg)
#define SE_OFF    405760u   // per (bh,s): rowsum(E)+decay*(q.n_loc)
#define NEND_OFF  471296u   // (32*8*128) local n at segment end -> n_start(j+1)
#define CEND_OFF  504064u   // (32*8*128*128) local C at segment end -> C_start(j+1)

__device__ __forceinline__ float logsig(float x){
  return (x >= 0.f) ? -log1pf(expf(-x)) : (x - log1pf(expf(x)));
}
__device__ __forceinline__ float dot4(float4 a, float4 b){
  return a.x*b.x + a.y*b.y + a.z*b.z + a.w*b.w;
}

// -------------------- K1: gates, LDS-tiled GEMM (16 rows x 16 gates / block)
__global__ __launch_bounds__(256) void k_gates(const float* __restrict__ q,
    const float* __restrict__ k, const float* __restrict__ v,
    const float* __restrict__ Wi, const float* __restrict__ bi,
    const float* __restrict__ Wf, const float* __restrict__ bf,
    float* __restrict__ ws){
  __shared__ __align__(16) float Xt[16][132];
  __shared__ __align__(16) float Wt[16][132];
  const int t = threadIdx.x;
  const int r0 = blockIdx.x * 16;
  const int rr = t >> 4, g = t & 15;
  float acc = 0.f;
  for (int kt = 0; kt < 24; kt++){
    const int src = kt >> 3;            // 0:q 1:k 2:v
    const int kb  = (kt & 7) << 7;      // 0..896
    const float* xs = (src==0) ? q : (src==1) ? k : v;
    __syncthreads();
    #pragma unroll
    for (int i=0;i<2;i++){
      int f = i*256 + t; int r = f>>5, d4 = f&31;
      ((float4*)&Xt[r][0])[d4] = *(const float4*)(xs + (size_t)(r0+r)*DIM_ + kb + 4*d4);
      const float* wrow = (r < 8) ? (Wi + (size_t)r*3072) : (Wf + (size_t)(r-8)*3072);
      ((float4*)&Wt[r][0])[d4] = *(const float4*)(wrow + src*1024 + kb + 4*d4);
    }
    __syncthreads();
    const float4* X4 = (const float4*)&Xt[rr][0];
    const float4* W4 = (const float4*)&Wt[g][0];
    #pragma unroll
    for (int d4=0; d4<32; d4++) acc += dot4(X4[d4], W4[d4]);
  }
  const int row = r0 + rr, b = row >> 11, s = row & 2047;
  if (g < 8){
    ws[IG_OFF + ((size_t)b*NH_ + g)*S_ + s] = acc + bi[g];
  } else {
    int h = g - 8;
    ws[LF_OFF + ((size_t)b*NH_ + h)*S_ + s] = logsig(acc + bf[h]);
  }
}

// ------------------- K2: chunk scalars + global m-scan + stab/decay + dp/dpf
__global__ __launch_bounds__(256) void k_mid(float* __restrict__ ws,
                                             float* __restrict__ ml_out){
  __shared__ float lfl_s[128], ml_s[128], a_s[128], b_s[128], mp_s[128];
  __shared__ float lfacc_sh[2048], R_sh[2048];
  int bh = blockIdx.x, t = threadIdx.x;
  if (t < 128){
    int n = t; size_t base = (size_t)bh*S_ + n*CS_;
    float lfacc[16], igr[16];
    float cum = 0.f;
    #pragma unroll
    for (int c=0;c<16;c++){ cum += ws[LF_OFF+base+c]; lfacc[c]=cum; igr[c]=ws[IG_OFF+base+c]; }
    float lfl = cum;
    float R = -3.4e38f;
    float Rr[16];
    #pragma unroll
    for (int c=0;c<16;c++){ R = fmaxf(R, igr[c]-lfacc[c]); Rr[c]=R; }
    float mloc = lfl + R;
    #pragma unroll
    for (int c=0;c<16;c++){
      ws[GEXP_OFF+base+c]  = expf(igr[c]-lfacc[c]+lfl-mloc);
      ws[LFACC_OFF+base+c] = lfacc[c];
      lfacc_sh[n*16+c] = lfacc[c];
      R_sh[n*16+c]     = Rr[c];
    }
    lfl_s[n]=lfl; ml_s[n]=mloc;
  }
  __syncthreads();
  if (t==0){
    float m = 0.f;
    for (int n=0;n<128;n++){
      float mn = fmaxf(lfl_s[n]+m, ml_s[n]);
      a_s[n]=expf(lfl_s[n]+m-mn); b_s[n]=expf(ml_s[n]-mn); mp_s[n]=m; m=mn;
    }
    ml_out[bh]=m;
  }
  __syncthreads();
  if (t < 128){ ws[A_OFF+bh*NS_+t]=a_s[t]; ws[BB_OFF+bh*NS_+t]=b_s[t]; }
  if (t < NSEG){
    float dp = 1.f;
    for (int i=0;i<SEGC;i++){
      int idx = t*SEGC + i;
      ws[DP_OFF + bh*NS_ + idx] = dp;
      dp *= a_s[idx];
    }
    ws[DPF_OFF + bh*NSEG + t] = dp;
  }
  for (int i=t; i<2048; i+=256){
    int n = i>>4;
    float la = lfacc_sh[i], mpv = mp_s[n];
    float stb = fmaxf(la + R_sh[i], mpv + la);
    ws[STAB_OFF +(size_t)bh*S_+i] = stb;
    ws[DECAY_OFF+(size_t)bh*S_+i] = expf(mpv + la - stb);
  }
}

// --------------------- K3: segmented local scan, W=32 e-tile, 512 threads
// grid 1024: eh = blk>>8 (0..3), bhseg = blk&255 (XCD-grouped siblings)
__global__ __launch_bounds__(512, 2) void k_seg(const float* __restrict__ qg,
    const float* __restrict__ kg, const float* __restrict__ vglob,
    float* __restrict__ ws, float* __restrict__ out){
  __shared__ __align__(16) float q_s[16][132];
  __shared__ __align__(16) float k_s[16][132];
  __shared__ __align__(16) float C_s[32][132];
  __shared__ float v_s[16][33], vg_s[16][33], E_s[16][17];
  __shared__ float n_s[128], pns_s[16];
  __shared__ float lfacc_s[16], ig_s[16], gexp_s[16], stab_s[16], decay_s[16];
  const int t  = threadIdx.x;
  const int eh = blockIdx.x >> 8;
  const int bhseg = blockIdx.x & 255;
  const int bh = bhseg >> 3, seg = bhseg & 7;
  const int b  = bh >> 3, h = bh & 7;
  const int e0 = eh*32;
  const int c_t = t >> 5, e_t = t & 31;       // P0(v)/P1/P3 mapping
  const int d_t = t & 127, g_t = t >> 7;      // P4 mapping (g_t 0..3)
  for (int i=t; i<32*132; i+=512) (&C_s[0][0])[i] = 0.f;
  if (t < 128) n_s[t] = 0.f;

  float4 pq, pk; float pv, pgx;
  float s_la=0.f, s_ig=0.f, s_gx=0.f, s_st=0.f, s_de=0.f, s_a, s_b;

#define LOADCH(nn) do { \
    const size_t rb = ((size_t)b*S_ + (size_t)(nn)*CS_)*DIM_ + (size_t)h*DH_; \
    const size_t sb = (size_t)bh*S_ + (size_t)(nn)*CS_; \
    pq = *(const float4*)(qg + rb + (size_t)c_t*2*DIM_ + (t&31)*4 + ((t>>4)&1)*DIM_); \
    pk = *(const float4*)(kg + rb + (size_t)c_t*2*DIM_ + (t&31)*4 + ((t>>4)&1)*DIM_); \
    pv  = vglob[rb + (size_t)c_t*DIM_ + e0 + e_t]; \
    pgx = ws[GEXP_OFF + sb + c_t]; \
    if (t < 16){ \
      s_la = ws[LFACC_OFF + sb + t]; \
      s_ig = ws[IG_OFF    + sb + t]; \
      s_gx = ws[GEXP_OFF  + sb + t]; \
      s_st = ws[STAB_OFF  + sb + t]; \
      s_de = ws[DECAY_OFF + sb + t]; \
    } \
    s_a = ws[A_OFF  + bh*NS_ + (nn)]; \
    s_b = ws[BB_OFF + bh*NS_ + (nn)]; \
  } while(0)
  // staging map for q/k: thread t covers row c = c_t*2 + ((t>>4)&1), float4 slot (t&15)... 
  // simpler: rows via idx arithmetic below must cover 16x128; recompute consistent map:
  // f = t in 0..511 -> r = f>>5 (0..15), d4 = f&31  == (c_t, e_t) reuse
#undef LOADCH
#define LOADCH(nn) do { \
    const size_t rb = ((size_t)b*S_ + (size_t)(nn)*CS_)*DIM_ + (size_t)h*DH_; \
    const size_t sb = (size_t)bh*S_ + (size_t)(nn)*CS_; \
    pq = *(const float4*)(qg + rb + (size_t)c_t*DIM_ + e_t*4); \
    pk = *(const float4*)(kg + rb + (size_t)c_t*DIM_ + e_t*4); \
    pv  = vglob[rb + (size_t)c_t*DIM_ + e0 + e_t]; \
    pgx = ws[GEXP_OFF + sb + c_t]; \
    if (t < 16){ \
      s_la = ws[LFACC_OFF + sb + t]; \
      s_ig = ws[IG_OFF    + sb + t]; \
      s_gx = ws[GEXP_OFF  + sb + t]; \
      s_st = ws[STAB_OFF  + sb + t]; \
      s_de = ws[DECAY_OFF + sb + t]; \
    } \
    s_a = ws[A_OFF  + bh*NS_ + (nn)]; \
    s_b = ws[BB_OFF + bh*NS_ + (nn)]; \
  } while(0)

  LOADCH(seg*SEGC);

  for (int ci=0; ci<SEGC; ci++){
    const int n = seg*SEGC + ci;
    const size_t rowbase = ((size_t)b*S_ + (size_t)n*CS_)*DIM_ + (size_t)h*DH_;
    __syncthreads();                 // prev P4 done; LDS free
    // ---- P0: staged regs -> LDS  (q row c_t, float4 slot e_t)
    ((float4*)&q_s[c_t][0])[e_t] = make_float4(pq.x*0.08838834764831845f,
        pq.y*0.08838834764831845f, pq.z*0.08838834764831845f, pq.w*0.08838834764831845f);
    ((float4*)&k_s[c_t][0])[e_t] = pk;
    v_s[c_t][e_t]  = pv;
    vg_s[c_t][e_t] = pv*pgx;
    if (t < 16){
      lfacc_s[t]=s_la; ig_s[t]=s_ig; gexp_s[t]=s_gx; stab_s[t]=s_st; decay_s[t]=s_de;
    }
    const float a_n = s_a, b_n = s_b;
    __syncthreads();
    if (ci < SEGC-1) LOADCH(n+1);    // prefetch hides under P1..P4
    // ---- P1: E (e_t<16) + IC (all 32 e) + pn partials
    float dqk = 0.f, ic = 0.f;
    {
      const float4* q4 = (const float4*)&q_s[c_t][0];
      const float4* k4 = (const float4*)&k_s[e_t & 15][0];
      const float4* C4 = (const float4*)&C_s[e_t][0];
      #pragma unroll
      for (int d4=0; d4<32; d4++){
        float4 qv = q4[d4];
        dqk += dot4(qv, k4[d4]);
        ic  += dot4(qv, C4[d4]);
      }
    }
    if (e_t < 16){
      float Ev = 0.f;
      if (e_t <= c_t)
        Ev = dqk * expf(lfacc_s[c_t] - lfacc_s[e_t] + ig_s[e_t] - stab_s[c_t]);
      E_s[c_t][e_t] = Ev;
    }
    {
      // pn: partial over 4 d's, then 32-lane shuffle reduce
      const int j = e_t;
      float p = 0.f;
      #pragma unroll
      for (int dd=0; dd<4; dd++) p += q_s[c_t][j*4+dd]*n_s[j*4+dd];
      #pragma unroll
      for (int off=16; off>0; off>>=1) p += __shfl_xor(p, off);
      if (j == 0) pns_s[c_t] = p;
    }
    __syncthreads();
    // ---- P3: h/U write (+ SE stats)
    {
      float rs = 0.f;
      #pragma unroll
      for (int cc=0;cc<16;cc++) rs += E_s[c_t][cc];
      float tot = rs + decay_s[c_t]*pns_s[c_t];
      float hs = 0.f;
      #pragma unroll
      for (int cc=0;cc<16;cc++) hs += E_s[c_t][cc]*v_s[cc][e_t];
      float val = hs + decay_s[c_t]*ic;
      size_t oaddr = rowbase + (size_t)c_t*DIM_ + e0 + e_t;
      if (seg == 0){
        float nrm = fmaxf(fabsf(tot), expf(-stab_s[c_t])) + EPSv;
        out[oaddr] = val/nrm;
      } else {
        out[oaddr] = val;
        if (eh==0 && e_t==0) ws[SE_OFF + (size_t)bh*S_ + n*CS_ + c_t] = tot;
      }
    }
    // ---- P4: kv + state update (C in LDS, n)
    {
      float kv[8] = {0,0,0,0,0,0,0,0};
      #pragma unroll
      for (int c=0;c<16;c++){
        float kc = k_s[c][d_t];
        #pragma unroll
        for (int j=0;j<8;j++) kv[j] += kc*vg_s[c][g_t*8+j];
      }
      #pragma unroll
      for (int j=0;j<8;j++){
        int e = g_t*8+j;
        C_s[e][d_t] = C_s[e][d_t]*a_n + kv[j]*b_n;
      }
      if (t < 128){
        float ks = 0.f;
        #pragma unroll
        for (int c=0;c<16;c++) ks += k_s[c][t]*gexp_s[c];
        n_s[t] = n_s[t]*a_n + ks*b_n;
      }
    }
  }
  __syncthreads();
  #pragma unroll
  for (int j=0;j<8;j++)
    ws[CEND_OFF + (size_t)bhseg*16384 + (size_t)(e0+g_t*8+j)*128 + d_t] = C_s[g_t*8+j][d_t];
  if (eh==0 && t<128) ws[NEND_OFF + bhseg*128 + t] = n_s[t];
#undef LOADCH
}

// ---------------------------------------- K4: combine segment boundary states
__global__ __launch_bounds__(256) void k_comb(float* __restrict__ ws,
    float* __restrict__ Cl, float* __restrict__ nl){
  int gid = blockIdx.x*256 + threadIdx.x;
  if (gid < 32*16384){
    int bh = gid >> 14, elem = gid & 16383;
    size_t base = CEND_OFF + (size_t)bh*131072 + elem;
    float S = 0.f;
    #pragma unroll
    for (int j=1;j<8;j++){
      float E = ws[base + (size_t)(j-1)*16384];
      S = E + ws[DPF_OFF + bh*NSEG + (j-1)]*S;
      ws[base + (size_t)(j-1)*16384] = S;
    }
    float cl = ws[base + (size_t)7*16384] + ws[DPF_OFF + bh*NSEG + 7]*S;
    int e = elem>>7, d = elem&127;
    Cl[(size_t)bh*16384 + (size_t)d*128 + e] = cl;
  } else {
    int i = gid - 32*16384;
    if (i < 4096){
      int bh = i>>7, d = i&127;
      size_t base = NEND_OFF + bh*1024 + d;
      float S = 0.f;
      #pragma unroll
      for (int j=1;j<8;j++){
        float E = ws[base + (j-1)*128];
        S = E + ws[DPF_OFF + bh*NSEG + (j-1)]*S;
        ws[base + (j-1)*128] = S;
      }
      nl[bh*128+d] = ws[base + 7*128] + ws[DPF_OFF + bh*NSEG + 7]*S;
    }
  }
}

// -------------- K5: cross-segment correction + normalization, W=32, 512 thr
// grid 896: eh = blk/224 (0..3), rem: bh = rem/7, seg = 1+rem%7
__global__ __launch_bounds__(512, 2) void k_corr(const float* __restrict__ qg,
    float* __restrict__ ws, float* __restrict__ out){
  __shared__ __align__(16) float Cs[32][132];
  __shared__ __align__(16) float q_s[16][132];
  __shared__ float nst[128], pns_s[16];
  __shared__ float se_s[16], stb_s[16], dcy_s[16];
  const int blk = blockIdx.x;
  const int eh  = blk / 224;
  const int rem = blk % 224;
  const int bh  = rem / 7, seg = 1 + rem % 7;
  const int b = bh>>3, h = bh&7, e0 = eh*32;
  const int t = threadIdx.x, c_t = t>>5, e_t = t&31;
  size_t cbase = CEND_OFF + ((size_t)bh*NSEG + seg-1)*16384;
  #pragma unroll
  for (int i=0;i<2;i++){
    int f = i*512+t; int el = f>>5, d4 = f&31;
    ((float4*)&Cs[el][0])[d4] = *(const float4*)(ws + cbase + (size_t)(e0+el)*128 + 4*d4);
  }
  if (t<128) nst[t] = ws[NEND_OFF + (bh*NSEG+seg-1)*128 + t];

  float4 pq;
  float s_se=0.f, s_st=0.f, s_de=0.f;
#define LOADQ(nn) do { \
    const size_t rb = ((size_t)b*S_ + (size_t)(nn)*CS_)*DIM_ + (size_t)h*DH_; \
    pq = *(const float4*)(qg + rb + (size_t)c_t*DIM_ + e_t*4); \
    if (t < 16){ \
      size_t sr = (size_t)bh*S_ + (nn)*CS_ + t; \
      s_se = ws[SE_OFF + sr]; s_st = ws[STAB_OFF + sr]; s_de = ws[DECAY_OFF + sr]; \
    } \
  } while(0)

  LOADQ(seg*SEGC);
  for (int ci=0; ci<SEGC; ci++){
    const int n = seg*SEGC + ci;
    const size_t rowbase = ((size_t)b*S_ + (size_t)n*CS_)*DIM_ + (size_t)h*DH_;
    __syncthreads();
    ((float4*)&q_s[c_t][0])[e_t] = make_float4(pq.x*0.08838834764831845f,
        pq.y*0.08838834764831845f, pq.z*0.08838834764831845f, pq.w*0.08838834764831845f);
    if (t < 16){ se_s[t]=s_se; stb_s[t]=s_st; dcy_s[t]=s_de; }
    const float dpn = ws[DP_OFF + bh*NS_ + n];
    __syncthreads();
    if (ci < SEGC-1) LOADQ(n+1);
    float corr = 0.f;
    {
      const float4* qq  = (const float4*)&q_s[c_t][0];
      const float4* cc4 = (const float4*)&Cs[e_t][0];
      #pragma unroll
      for (int d4=0; d4<32; d4++) corr += dot4(qq[d4], cc4[d4]);
    }
    {
      const int j = e_t;
      float p = 0.f;
      #pragma unroll
      for (int dd=0;dd<4;dd++) p += q_s[c_t][j*4+dd]*nst[j*4+dd];
      #pragma unroll
      for (int off=16; off>0; off>>=1) p += __shfl_xor(p, off);
      if (j==0) pns_s[c_t] = p;
    }
    __syncthreads();
    {
      float dcp = dcy_s[c_t] * dpn;
      float denom = se_s[c_t] + dcp*pns_s[c_t];
      float nrm = fmaxf(fabsf(denom), expf(-stb_s[c_t])) + EPSv;
      size_t oaddr = rowbase + (size_t)c_t*DIM_ + e0 + e_t;
      out[oaddr] = (out[oaddr] + dcp*corr)/nrm;
    }
  }
#undef LOADQ
}

// ------------------------------------------------------ K6: in-place LN
__global__ __launch_bounds__(256) void k_ln(float* __restrict__ out,
    const float* __restrict__ lnw, const float* __restrict__ lnb){
  int r = blockIdx.x*4 + (threadIdx.x>>6);
  int lane = threadIdx.x & 63;
  int b = r >> 14;
  int h = (r >> 11) & 7;
  int s = r & 2047;
  size_t base = ((size_t)b*S_ + s)*DIM_ + (size_t)h*DH_;
  float2 x = *(const float2*)&out[base + lane*2];
  float sm = x.x + x.y;
  #pragma unroll
  for (int off=32; off>0; off>>=1) sm += __shfl_xor(sm, off, 64);
  float mu = sm * (1.0f/128.0f);
  float d0 = x.x-mu, d1 = x.y-mu;
  float ss = d0*d0 + d1*d1;
  #pragma unroll
  for (int off=32; off>0; off>>=1) ss += __shfl_xor(ss, off, 64);
  float rstd = 1.0f/sqrtf(ss*(1.0f/128.0f) + LNEPS);
  int wi = h*DH_ + lane*2;
  float2 w2 = *(const float2*)&lnw[wi];
  float2 b2 = *(const float2*)&lnb[wi];
  float2 y;
  y.x = d0*rstd*(1.0f+w2.x) + b2.x;
  y.y = d1*rstd*(1.0f+w2.y) + b2.y;
  *(float2*)&out[base + lane*2] = y;
}

extern "C" void kernel_launch(void* const* d_in, const int* in_sizes, int n_in,
                              void* d_out, int out_size, void* d_ws, size_t ws_size,
                              hipStream_t stream){
  const float* q   = (const float*)d_in[0];
  const float* k   = (const float*)d_in[1];
  const float* v   = (const float*)d_in[2];
  const float* Wi  = (const float*)d_in[3];
  const float* bi  = (const float*)d_in[4];
  const float* Wf  = (const float*)d_in[5];
  const float* bf  = (const float*)d_in[6];
  const float* lnw = (const float*)d_in[7];
  const float* lnb = (const float*)d_in[8];
  float* out = (float*)d_out;                 // (B,S,DIM)
  float* Cl  = out + 8388608;                 // (B,NH,DH,DH)
  float* nl  = out + 8912896;                 // (B,NH,DH)
  float* ml  = out + 8916992;                 // (B,NH,1,1)
  float* ws  = (float*)d_ws;

  k_gates<<<512,  256, 0, stream>>>(q,k,v,Wi,bi,Wf,bf,ws);
  k_mid  <<<32,   256, 0, stream>>>(ws, ml);
  k_seg  <<<1024, 512, 0, stream>>>(q,k,v,ws,out);
  k_comb <<<2064, 256, 0, stream>>>(ws, Cl, nl);
  k_corr <<<896,  512, 0, stream>>>(q, ws, out);
  k_ln   <<<16384,256, 0, stream>>>(out, lnw, lnb);
}

// Round 7
// 2363.791 us; speedup vs baseline: 1.0025x; 1.0025x over previous
//
#include <hip/hip_runtime.h>
#include <math.h>

#define B_   4
#define S_   2048
#define DIM_ 1024
#define NH_  8
#define DH_  128
#define CS_  16
#define NS_  128
#define NSEG 8
#define SEGC 16          // chunks per segment
#define EPSv  1e-6f
#define LNEPS 1e-5f

// workspace layout (float offsets) — total 4,698,368 floats = 18.8 MB
#define IG_OFF    0u        // (B*NH*S)
#define LF_OFF    65536u
#define LFACC_OFF 131072u
#define GEXP_OFF  196608u
#define STAB_OFF  262144u
#define DECAY_OFF 327680u
#define A_OFF     393216u   // (B*NH*NS)
#define BB_OFF    397312u
#define DP_OFF    401408u   // decay-product from segment start (exclusive), per chunk
#define DPF_OFF   405504u   // full-segment decay product, per (bh,seg)
#define SE_OFF    405760u   // per (bh,s): rowsum(E)+decay*(q.n_loc)
#define NEND_OFF  471296u   // (32*8*128) local n at segment end -> n_start(j+1)
#define CEND_OFF  504064u   // (32*8*128*128) local C at segment end -> C_start(j+1)

__device__ __forceinline__ float logsig(float x){
  return (x >= 0.f) ? -log1pf(expf(-x)) : (x - log1pf(expf(x)));
}
__device__ __forceinline__ float dot4(float4 a, float4 b){
  return a.x*b.x + a.y*b.y + a.z*b.z + a.w*b.w;
}

// -------------------- K1: gates, LDS-tiled GEMM (16 rows x 16 gates / block)
__global__ __launch_bounds__(256) void k_gates(const float* __restrict__ q,
    const float* __restrict__ k, const float* __restrict__ v,
    const float* __restrict__ Wi, const float* __restrict__ bi,
    const float* __restrict__ Wf, const float* __restrict__ bf,
    float* __restrict__ ws){
  __shared__ __align__(16) float Xt[16][132];
  __shared__ __align__(16) float Wt[16][132];
  const int t = threadIdx.x;
  const int r0 = blockIdx.x * 16;
  const int rr = t >> 4, g = t & 15;
  float acc = 0.f;
  for (int kt = 0; kt < 24; kt++){
    const int src = kt >> 3;            // 0:q 1:k 2:v
    const int kb  = (kt & 7) << 7;      // 0..896
    const float* xs = (src==0) ? q : (src==1) ? k : v;
    __syncthreads();
    #pragma unroll
    for (int i=0;i<2;i++){
      int f = i*256 + t; int r = f>>5, d4 = f&31;
      ((float4*)&Xt[r][0])[d4] = *(const float4*)(xs + (size_t)(r0+r)*DIM_ + kb + 4*d4);
      const float* wrow = (r < 8) ? (Wi + (size_t)r*3072) : (Wf + (size_t)(r-8)*3072);
      ((float4*)&Wt[r][0])[d4] = *(const float4*)(wrow + src*1024 + kb + 4*d4);
    }
    __syncthreads();
    const float4* X4 = (const float4*)&Xt[rr][0];
    const float4* W4 = (const float4*)&Wt[g][0];
    #pragma unroll
    for (int d4=0; d4<32; d4++) acc += dot4(X4[d4], W4[d4]);
  }
  const int row = r0 + rr, b = row >> 11, s = row & 2047;
  if (g < 8){
    ws[IG_OFF + ((size_t)b*NH_ + g)*S_ + s] = acc + bi[g];
  } else {
    int h = g - 8;
    ws[LF_OFF + ((size_t)b*NH_ + h)*S_ + s] = logsig(acc + bf[h]);
  }
}

// ------------------- K2: chunk scalars + global m-scan + stab/decay + dp/dpf
__global__ __launch_bounds__(256) void k_mid(float* __restrict__ ws,
                                             float* __restrict__ ml_out){
  __shared__ float lfl_s[128], ml_s[128], a_s[128], b_s[128], mp_s[128];
  __shared__ float lfacc_sh[2048], R_sh[2048];
  int bh = blockIdx.x, t = threadIdx.x;
  if (t < 128){
    int n = t; size_t base = (size_t)bh*S_ + n*CS_;
    float lfacc[16], igr[16];
    float cum = 0.f;
    #pragma unroll
    for (int c=0;c<16;c++){ cum += ws[LF_OFF+base+c]; lfacc[c]=cum; igr[c]=ws[IG_OFF+base+c]; }
    float lfl = cum;
    float R = -3.4e38f;
    float Rr[16];
    #pragma unroll
    for (int c=0;c<16;c++){ R = fmaxf(R, igr[c]-lfacc[c]); Rr[c]=R; }
    float mloc = lfl + R;
    #pragma unroll
    for (int c=0;c<16;c++){
      ws[GEXP_OFF+base+c]  = expf(igr[c]-lfacc[c]+lfl-mloc);
      ws[LFACC_OFF+base+c] = lfacc[c];
      lfacc_sh[n*16+c] = lfacc[c];
      R_sh[n*16+c]     = Rr[c];
    }
    lfl_s[n]=lfl; ml_s[n]=mloc;
  }
  __syncthreads();
  if (t==0){
    float m = 0.f;
    for (int n=0;n<128;n++){
      float mn = fmaxf(lfl_s[n]+m, ml_s[n]);
      a_s[n]=expf(lfl_s[n]+m-mn); b_s[n]=expf(ml_s[n]-mn); mp_s[n]=m; m=mn;
    }
    ml_out[bh]=m;
  }
  __syncthreads();
  if (t < 128){ ws[A_OFF+bh*NS_+t]=a_s[t]; ws[BB_OFF+bh*NS_+t]=b_s[t]; }
  if (t < NSEG){
    float dp = 1.f;
    for (int i=0;i<SEGC;i++){
      int idx = t*SEGC + i;
      ws[DP_OFF + bh*NS_ + idx] = dp;
      dp *= a_s[idx];
    }
    ws[DPF_OFF + bh*NSEG + t] = dp;
  }
  for (int i=t; i<2048; i+=256){
    int n = i>>4;
    float la = lfacc_sh[i], mpv = mp_s[n];
    float stb = fmaxf(la + R_sh[i], mpv + la);
    ws[STAB_OFF +(size_t)bh*S_+i] = stb;
    ws[DECAY_OFF+(size_t)bh*S_+i] = expf(mpv + la - stb);
  }
}

// --------------------- K3: segmented local scan, W=32 e-tile, 512 threads
// grid 1024: eh = blk>>8 (0..3), bhseg = blk&255
// NOTE: __launch_bounds__(512, 1): a 512-thread block already forces 2 waves/EU;
// min-waves=2 capped VGPR at 128 and spilled ~6.5 GB of scratch traffic (round 6).
__global__ __launch_bounds__(512, 1) void k_seg(const float* __restrict__ qg,
    const float* __restrict__ kg, const float* __restrict__ vglob,
    float* __restrict__ ws, float* __restrict__ out){
  __shared__ __align__(16) float q_s[16][132];
  __shared__ __align__(16) float k_s[16][132];
  __shared__ __align__(16) float C_s[32][132];
  __shared__ float v_s[16][33], vg_s[16][33], E_s[16][17];
  __shared__ float n_s[128], pns_s[16];
  __shared__ float lfacc_s[16], ig_s[16], gexp_s[16], stab_s[16], decay_s[16];
  const int t  = threadIdx.x;
  const int eh = blockIdx.x >> 8;
  const int bhseg = blockIdx.x & 255;
  const int bh = bhseg >> 3, seg = bhseg & 7;
  const int b  = bh >> 3, h = bh & 7;
  const int e0 = eh*32;
  const int c_t = t >> 5, e_t = t & 31;       // P0/P1/P3 mapping
  const int d_t = t & 127, g_t = t >> 7;      // P4 mapping (g_t 0..3)
  for (int i=t; i<32*132; i+=512) (&C_s[0][0])[i] = 0.f;
  if (t < 128) n_s[t] = 0.f;

  float4 pq, pk; float pv, pgx;
  float s_la=0.f, s_ig=0.f, s_gx=0.f, s_st=0.f, s_de=0.f, s_a, s_b;

#define LOADCH(nn) do { \
    const size_t rb = ((size_t)b*S_ + (size_t)(nn)*CS_)*DIM_ + (size_t)h*DH_; \
    const size_t sb = (size_t)bh*S_ + (size_t)(nn)*CS_; \
    pq = *(const float4*)(qg + rb + (size_t)c_t*DIM_ + e_t*4); \
    pk = *(const float4*)(kg + rb + (size_t)c_t*DIM_ + e_t*4); \
    pv  = vglob[rb + (size_t)c_t*DIM_ + e0 + e_t]; \
    pgx = ws[GEXP_OFF + sb + c_t]; \
    if (t < 16){ \
      s_la = ws[LFACC_OFF + sb + t]; \
      s_ig = ws[IG_OFF    + sb + t]; \
      s_gx = ws[GEXP_OFF  + sb + t]; \
      s_st = ws[STAB_OFF  + sb + t]; \
      s_de = ws[DECAY_OFF + sb + t]; \
    } \
    s_a = ws[A_OFF  + bh*NS_ + (nn)]; \
    s_b = ws[BB_OFF + bh*NS_ + (nn)]; \
  } while(0)

  LOADCH(seg*SEGC);

  for (int ci=0; ci<SEGC; ci++){
    const int n = seg*SEGC + ci;
    const size_t rowbase = ((size_t)b*S_ + (size_t)n*CS_)*DIM_ + (size_t)h*DH_;
    __syncthreads();                 // prev P4 done; LDS free
    // ---- P0: staged regs -> LDS  (q row c_t, float4 slot e_t)
    ((float4*)&q_s[c_t][0])[e_t] = make_float4(pq.x*0.08838834764831845f,
        pq.y*0.08838834764831845f, pq.z*0.08838834764831845f, pq.w*0.08838834764831845f);
    ((float4*)&k_s[c_t][0])[e_t] = pk;
    v_s[c_t][e_t]  = pv;
    vg_s[c_t][e_t] = pv*pgx;
    if (t < 16){
      lfacc_s[t]=s_la; ig_s[t]=s_ig; gexp_s[t]=s_gx; stab_s[t]=s_st; decay_s[t]=s_de;
    }
    const float a_n = s_a, b_n = s_b;
    __syncthreads();
    if (ci < SEGC-1) LOADCH(n+1);    // prefetch hides under P1..P4
    // ---- P1: E (e_t<16) + IC (all 32 e) + pn partials
    float dqk = 0.f, ic = 0.f;
    {
      const float4* q4 = (const float4*)&q_s[c_t][0];
      const float4* k4 = (const float4*)&k_s[e_t & 15][0];
      const float4* C4 = (const float4*)&C_s[e_t][0];
      #pragma unroll
      for (int d4=0; d4<32; d4++){
        float4 qv = q4[d4];
        dqk += dot4(qv, k4[d4]);
        ic  += dot4(qv, C4[d4]);
      }
    }
    if (e_t < 16){
      float Ev = 0.f;
      if (e_t <= c_t)
        Ev = dqk * expf(lfacc_s[c_t] - lfacc_s[e_t] + ig_s[e_t] - stab_s[c_t]);
      E_s[c_t][e_t] = Ev;
    }
    {
      // pn: partial over 4 d's, then 32-lane shuffle reduce
      const int j = e_t;
      float p = 0.f;
      #pragma unroll
      for (int dd=0; dd<4; dd++) p += q_s[c_t][j*4+dd]*n_s[j*4+dd];
      #pragma unroll
      for (int off=16; off>0; off>>=1) p += __shfl_xor(p, off);
      if (j == 0) pns_s[c_t] = p;
    }
    __syncthreads();
    // ---- P3: h/U write (+ SE stats)
    {
      float rs = 0.f;
      #pragma unroll
      for (int cc=0;cc<16;cc++) rs += E_s[c_t][cc];
      float tot = rs + decay_s[c_t]*pns_s[c_t];
      float hs = 0.f;
      #pragma unroll
      for (int cc=0;cc<16;cc++) hs += E_s[c_t][cc]*v_s[cc][e_t];
      float val = hs + decay_s[c_t]*ic;
      size_t oaddr = rowbase + (size_t)c_t*DIM_ + e0 + e_t;
      if (seg == 0){
        float nrm = fmaxf(fabsf(tot), expf(-stab_s[c_t])) + EPSv;
        out[oaddr] = val/nrm;
      } else {
        out[oaddr] = val;
        if (eh==0 && e_t==0) ws[SE_OFF + (size_t)bh*S_ + n*CS_ + c_t] = tot;
      }
    }
    // ---- P4: kv + state update (C in LDS, n)
    {
      float kv[8] = {0,0,0,0,0,0,0,0};
      #pragma unroll
      for (int c=0;c<16;c++){
        float kc = k_s[c][d_t];
        #pragma unroll
        for (int j=0;j<8;j++) kv[j] += kc*vg_s[c][g_t*8+j];
      }
      #pragma unroll
      for (int j=0;j<8;j++){
        int e = g_t*8+j;
        C_s[e][d_t] = C_s[e][d_t]*a_n + kv[j]*b_n;
      }
      if (t < 128){
        float ks = 0.f;
        #pragma unroll
        for (int c=0;c<16;c++) ks += k_s[c][t]*gexp_s[c];
        n_s[t] = n_s[t]*a_n + ks*b_n;
      }
    }
  }
  __syncthreads();
  #pragma unroll
  for (int j=0;j<8;j++)
    ws[CEND_OFF + (size_t)bhseg*16384 + (size_t)(e0+g_t*8+j)*128 + d_t] = C_s[g_t*8+j][d_t];
  if (eh==0 && t<128) ws[NEND_OFF + bhseg*128 + t] = n_s[t];
#undef LOADCH
}

// ---------------------------------------- K4: combine segment boundary states
__global__ __launch_bounds__(256) void k_comb(float* __restrict__ ws,
    float* __restrict__ Cl, float* __restrict__ nl){
  int gid = blockIdx.x*256 + threadIdx.x;
  if (gid < 32*16384){
    int bh = gid >> 14, elem = gid & 16383;
    size_t base = CEND_OFF + (size_t)bh*131072 + elem;
    float S = 0.f;
    #pragma unroll
    for (int j=1;j<8;j++){
      float E = ws[base + (size_t)(j-1)*16384];
      S = E + ws[DPF_OFF + bh*NSEG + (j-1)]*S;
      ws[base + (size_t)(j-1)*16384] = S;
    }
    float cl = ws[base + (size_t)7*16384] + ws[DPF_OFF + bh*NSEG + 7]*S;
    int e = elem>>7, d = elem&127;
    Cl[(size_t)bh*16384 + (size_t)d*128 + e] = cl;
  } else {
    int i = gid - 32*16384;
    if (i < 4096){
      int bh = i>>7, d = i&127;
      size_t base = NEND_OFF + bh*1024 + d;
      float S = 0.f;
      #pragma unroll
      for (int j=1;j<8;j++){
        float E = ws[base + (j-1)*128];
        S = E + ws[DPF_OFF + bh*NSEG + (j-1)]*S;
        ws[base + (j-1)*128] = S;
      }
      nl[bh*128+d] = ws[base + 7*128] + ws[DPF_OFF + bh*NSEG + 7]*S;
    }
  }
}

// -------------- K5: cross-segment correction + normalization, W=32, 512 thr
// grid 896: eh = blk/224 (0..3), rem: bh = rem/7, seg = 1+rem%7
__global__ __launch_bounds__(512, 1) void k_corr(const float* __restrict__ qg,
    float* __restrict__ ws, float* __restrict__ out){
  __shared__ __align__(16) float Cs[32][132];
  __shared__ __align__(16) float q_s[16][132];
  __shared__ float nst[128], pns_s[16];
  __shared__ float se_s[16], stb_s[16], dcy_s[16];
  const int blk = blockIdx.x;
  const int eh  = blk / 224;
  const int rem = blk % 224;
  const int bh  = rem / 7, seg = 1 + rem % 7;
  const int b = bh>>3, h = bh&7, e0 = eh*32;
  const int t = threadIdx.x, c_t = t>>5, e_t = t&31;
  size_t cbase = CEND_OFF + ((size_t)bh*NSEG + seg-1)*16384;
  #pragma unroll
  for (int i=0;i<2;i++){
    int f = i*512+t; int el = f>>5, d4 = f&31;
    ((float4*)&Cs[el][0])[d4] = *(const float4*)(ws + cbase + (size_t)(e0+el)*128 + 4*d4);
  }
  if (t<128) nst[t] = ws[NEND_OFF + (bh*NSEG+seg-1)*128 + t];

  float4 pq;
  float s_se=0.f, s_st=0.f, s_de=0.f;
#define LOADQ(nn) do { \
    const size_t rb = ((size_t)b*S_ + (size_t)(nn)*CS_)*DIM_ + (size_t)h*DH_; \
    pq = *(const float4*)(qg + rb + (size_t)c_t*DIM_ + e_t*4); \
    if (t < 16){ \
      size_t sr = (size_t)bh*S_ + (nn)*CS_ + t; \
      s_se = ws[SE_OFF + sr]; s_st = ws[STAB_OFF + sr]; s_de = ws[DECAY_OFF + sr]; \
    } \
  } while(0)

  LOADQ(seg*SEGC);
  for (int ci=0; ci<SEGC; ci++){
    const int n = seg*SEGC + ci;
    const size_t rowbase = ((size_t)b*S_ + (size_t)n*CS_)*DIM_ + (size_t)h*DH_;
    __syncthreads();
    ((float4*)&q_s[c_t][0])[e_t] = make_float4(pq.x*0.08838834764831845f,
        pq.y*0.08838834764831845f, pq.z*0.08838834764831845f, pq.w*0.08838834764831845f);
    if (t < 16){ se_s[t]=s_se; stb_s[t]=s_st; dcy_s[t]=s_de; }
    const float dpn = ws[DP_OFF + bh*NS_ + n];
    __syncthreads();
    if (ci < SEGC-1) LOADQ(n+1);
    float corr = 0.f;
    {
      const float4* qq  = (const float4*)&q_s[c_t][0];
      const float4* cc4 = (const float4*)&Cs[e_t][0];
      #pragma unroll
      for (int d4=0; d4<32; d4++) corr += dot4(qq[d4], cc4[d4]);
    }
    {
      const int j = e_t;
      float p = 0.f;
      #pragma unroll
      for (int dd=0;dd<4;dd++) p += q_s[c_t][j*4+dd]*nst[j*4+dd];
      #pragma unroll
      for (int off=16; off>0; off>>=1) p += __shfl_xor(p, off);
      if (j==0) pns_s[c_t] = p;
    }
    __syncthreads();
    {
      float dcp = dcy_s[c_t] * dpn;
      float denom = se_s[c_t] + dcp*pns_s[c_t];
      float nrm = fmaxf(fabsf(denom), expf(-stb_s[c_t])) + EPSv;
      size_t oaddr = rowbase + (size_t)c_t*DIM_ + e0 + e_t;
      out[oaddr] = (out[oaddr] + dcp*corr)/nrm;
    }
  }
#undef LOADQ
}

// ------------------------------------------------------ K6: in-place LN
__global__ __launch_bounds__(256) void k_ln(float* __restrict__ out,
    const float* __restrict__ lnw, const float* __restrict__ lnb){
  int r = blockIdx.x*4 + (threadIdx.x>>6);
  int lane = threadIdx.x & 63;
  int b = r >> 14;
  int h = (r >> 11) & 7;
  int s = r & 2047;
  size_t base = ((size_t)b*S_ + s)*DIM_ + (size_t)h*DH_;
  float2 x = *(const float2*)&out[base + lane*2];
  float sm = x.x + x.y;
  #pragma unroll
  for (int off=32; off>0; off>>=1) sm += __shfl_xor(sm, off, 64);
  float mu = sm * (1.0f/128.0f);
  float d0 = x.x-mu, d1 = x.y-mu;
  float ss = d0*d0 + d1*d1;
  #pragma unroll
  for (int off=32; off>0; off>>=1) ss += __shfl_xor(ss, off, 64);
  float rstd = 1.0f/sqrtf(ss*(1.0f/128.0f) + LNEPS);
  int wi = h*DH_ + lane*2;
  float2 w2 = *(const float2*)&lnw[wi];
  float2 b2 = *(const float2*)&lnb[wi];
  float2 y;
  y.x = d0*rstd*(1.0f+w2.x) + b2.x;
  y.y = d1*rstd*(1.0f+w2.y) + b2.y;
  *(float2*)&out[base + lane*2] = y;
}

extern "C" void kernel_launch(void* const* d_in, const int* in_sizes, int n_in,
                              void* d_out, int out_size, void* d_ws, size_t ws_size,
                              hipStream_t stream){
  const float* q   = (const float*)d_in[0];
  const float* k   = (const float*)d_in[1];
  const float* v   = (const float*)d_in[2];
  const float* Wi  = (const float*)d_in[3];
  const float* bi  = (const float*)d_in[4];
  const float* Wf  = (const float*)d_in[5];
  const float* bf  = (const float*)d_in[6];
  const float* lnw = (const float*)d_in[7];
  const float* lnb = (const float*)d_in[8];
  float* out = (float*)d_out;                 // (B,S,DIM)
  float* Cl  = out + 8388608;                 // (B,NH,DH,DH)
  float* nl  = out + 8912896;                 // (B,NH,DH)
  float* ml  = out + 8916992;                 // (B,NH,1,1)
  float* ws  = (float*)d_ws;

  k_gates<<<512,  256, 0, stream>>>(q,k,v,Wi,bi,Wf,bf,ws);
  k_mid  <<<32,   256, 0, stream>>>(ws, ml);
  k_seg  <<<1024, 512, 0, stream>>>(q,k,v,ws,out);
  k_comb <<<2064, 256, 0, stream>>>(ws, Cl, nl);
  k_corr <<<896,  512, 0, stream>>>(q, ws, out);
  k_ln   <<<16384,256, 0, stream>>>(out, lnw, lnb);
}

// Round 8
// 525.045 us; speedup vs baseline: 4.5134x; 4.5021x over previous
//
#include <hip/hip_runtime.h>
#include <math.h>

#define B_   4
#define S_   2048
#define DIM_ 1024
#define NH_  8
#define DH_  128
#define CS_  16
#define NS_  128
#define NSEG 8
#define SEGC 16          // chunks per segment
#define EPSv  1e-6f
#define LNEPS 1e-5f

// workspace layout (float offsets) — total 4,698,368 floats = 18.8 MB
#define IG_OFF    0u        // (B*NH*S)
#define LF_OFF    65536u
#define LFACC_OFF 131072u
#define GEXP_OFF  196608u
#define STAB_OFF  262144u
#define DECAY_OFF 327680u
#define A_OFF     393216u   // (B*NH*NS)
#define BB_OFF    397312u
#define DP_OFF    401408u   // decay-product from segment start (exclusive), per chunk
#define DPF_OFF   405504u   // full-segment decay product, per (bh,seg)
#define SE_OFF    405760u   // per (bh,s): rowsum(E)+decay*(q.n_loc)
#define NEND_OFF  471296u   // (32*8*128) local n at segment end -> n_start(j+1)
#define CEND_OFF  504064u   // (32*8*128*128) local C at segment end -> C_start(j+1)

__device__ __forceinline__ float logsig(float x){
  return (x >= 0.f) ? -log1pf(expf(-x)) : (x - log1pf(expf(x)));
}
__device__ __forceinline__ float dot4(float4 a, float4 b){
  return a.x*b.x + a.y*b.y + a.z*b.z + a.w*b.w;
}

// -------------------- K1: gates, LDS-tiled GEMM (16 rows x 16 gates / block)
__global__ __launch_bounds__(256) void k_gates(const float* __restrict__ q,
    const float* __restrict__ k, const float* __restrict__ v,
    const float* __restrict__ Wi, const float* __restrict__ bi,
    const float* __restrict__ Wf, const float* __restrict__ bf,
    float* __restrict__ ws){
  __shared__ __align__(16) float Xt[16][132];
  __shared__ __align__(16) float Wt[16][132];
  const int t = threadIdx.x;
  const int r0 = blockIdx.x * 16;
  const int rr = t >> 4, g = t & 15;
  float acc = 0.f;
  for (int kt = 0; kt < 24; kt++){
    const int src = kt >> 3;            // 0:q 1:k 2:v
    const int kb  = (kt & 7) << 7;      // 0..896
    const float* xs = (src==0) ? q : (src==1) ? k : v;
    __syncthreads();
    #pragma unroll
    for (int i=0;i<2;i++){
      int f = i*256 + t; int r = f>>5, d4 = f&31;
      ((float4*)&Xt[r][0])[d4] = *(const float4*)(xs + (size_t)(r0+r)*DIM_ + kb + 4*d4);
      const float* wrow = (r < 8) ? (Wi + (size_t)r*3072) : (Wf + (size_t)(r-8)*3072);
      ((float4*)&Wt[r][0])[d4] = *(const float4*)(wrow + src*1024 + kb + 4*d4);
    }
    __syncthreads();
    const float4* X4 = (const float4*)&Xt[rr][0];
    const float4* W4 = (const float4*)&Wt[g][0];
    #pragma unroll 4
    for (int d4=0; d4<32; d4++) acc += dot4(X4[d4], W4[d4]);
  }
  const int row = r0 + rr, b = row >> 11, s = row & 2047;
  if (g < 8){
    ws[IG_OFF + ((size_t)b*NH_ + g)*S_ + s] = acc + bi[g];
  } else {
    int h = g - 8;
    ws[LF_OFF + ((size_t)b*NH_ + h)*S_ + s] = logsig(acc + bf[h]);
  }
}

// ------------------- K2: chunk scalars + global m-scan + stab/decay + dp/dpf
__global__ __launch_bounds__(256) void k_mid(float* __restrict__ ws,
                                             float* __restrict__ ml_out){
  __shared__ float lfl_s[128], ml_s[128], a_s[128], b_s[128], mp_s[128];
  __shared__ float lfacc_sh[2048], R_sh[2048];
  int bh = blockIdx.x, t = threadIdx.x;
  if (t < 128){
    int n = t; size_t base = (size_t)bh*S_ + n*CS_;
    float lfacc[16], igr[16];
    float cum = 0.f;
    #pragma unroll
    for (int c=0;c<16;c++){ cum += ws[LF_OFF+base+c]; lfacc[c]=cum; igr[c]=ws[IG_OFF+base+c]; }
    float lfl = cum;
    float R = -3.4e38f;
    float Rr[16];
    #pragma unroll
    for (int c=0;c<16;c++){ R = fmaxf(R, igr[c]-lfacc[c]); Rr[c]=R; }
    float mloc = lfl + R;
    #pragma unroll
    for (int c=0;c<16;c++){
      ws[GEXP_OFF+base+c]  = expf(igr[c]-lfacc[c]+lfl-mloc);
      ws[LFACC_OFF+base+c] = lfacc[c];
      lfacc_sh[n*16+c] = lfacc[c];
      R_sh[n*16+c]     = Rr[c];
    }
    lfl_s[n]=lfl; ml_s[n]=mloc;
  }
  __syncthreads();
  if (t==0){
    float m = 0.f;
    for (int n=0;n<128;n++){
      float mn = fmaxf(lfl_s[n]+m, ml_s[n]);
      a_s[n]=expf(lfl_s[n]+m-mn); b_s[n]=expf(ml_s[n]-mn); mp_s[n]=m; m=mn;
    }
    ml_out[bh]=m;
  }
  __syncthreads();
  if (t < 128){ ws[A_OFF+bh*NS_+t]=a_s[t]; ws[BB_OFF+bh*NS_+t]=b_s[t]; }
  if (t < NSEG){
    float dp = 1.f;
    for (int i=0;i<SEGC;i++){
      int idx = t*SEGC + i;
      ws[DP_OFF + bh*NS_ + idx] = dp;
      dp *= a_s[idx];
    }
    ws[DPF_OFF + bh*NSEG + t] = dp;
  }
  for (int i=t; i<2048; i+=256){
    int n = i>>4;
    float la = lfacc_sh[i], mpv = mp_s[n];
    float stb = fmaxf(la + R_sh[i], mpv + la);
    ws[STAB_OFF +(size_t)bh*S_+i] = stb;
    ws[DECAY_OFF+(size_t)bh*S_+i] = expf(mpv + la - stb);
  }
}

// --------------------- K3: segmented local scan, 256 thr, W=16 e-tile
// grid 2048: eh = blk>>8 (0..7), bhseg = blk&255
// 256-thr blocks: compiler allocates freely (192 max observed, no spill).
// No cross-phase prefetch + unroll 4: minimize VGPR so 2-4 blocks/CU co-reside.
__global__ __launch_bounds__(256) void k_seg(const float* __restrict__ qg,
    const float* __restrict__ kg, const float* __restrict__ vglob,
    float* __restrict__ ws, float* __restrict__ out){
  __shared__ __align__(16) float q_s[16][132];
  __shared__ __align__(16) float k_s[16][132];
  __shared__ __align__(16) float C_s[16][132];
  __shared__ float v_s[16][17], vg_s[16][17], E_s[16][17], pn_s[16][9];
  __shared__ float n_s[128];
  __shared__ float lfacc_s[16], ig_s[16], gexp_s[16], stab_s[16], decay_s[16];
  const int t  = threadIdx.x;
  const int eh = blockIdx.x >> 8;
  const int bhseg = blockIdx.x & 255;
  const int bh = bhseg >> 3, seg = bhseg & 7;
  const int b  = bh >> 3, h = bh & 7;
  const int e0 = eh*CS_;
  const int c_t = t >> 4, e_t = t & 15;
  const int d_t = t & 127, g_t = t >> 7;
  for (int i=t; i<16*132; i+=256) (&C_s[0][0])[i] = 0.f;
  if (t < 128) n_s[t] = 0.f;

  for (int ci=0; ci<SEGC; ci++){
    const int n = seg*SEGC + ci;
    const size_t rowbase = ((size_t)b*S_ + (size_t)n*CS_)*DIM_ + (size_t)h*DH_;
    const size_t sbase   = (size_t)bh*S_ + (size_t)n*CS_;
    __syncthreads();                 // prev chunk's readers done; LDS reusable
    // ---- P0: direct global -> LDS staging (no cross-phase registers)
    #pragma unroll
    for (int i=0;i<2;i++){
      int f = i*256 + t; int r = f>>5, d4 = f&31;
      float4 qv = *(const float4*)(qg + rowbase + (size_t)r*DIM_ + 4*d4);
      ((float4*)&q_s[r][0])[d4] = make_float4(qv.x*0.08838834764831845f,
          qv.y*0.08838834764831845f, qv.z*0.08838834764831845f, qv.w*0.08838834764831845f);
      ((float4*)&k_s[r][0])[d4] = *(const float4*)(kg + rowbase + (size_t)r*DIM_ + 4*d4);
    }
    {
      float vv = vglob[rowbase + (size_t)c_t*DIM_ + e0 + e_t];
      float gx = ws[GEXP_OFF + sbase + c_t];
      v_s[c_t][e_t] = vv; vg_s[c_t][e_t] = vv*gx;
    }
    if (t < 16){
      lfacc_s[t] = ws[LFACC_OFF + sbase + t];
      ig_s[t]    = ws[IG_OFF    + sbase + t];
      gexp_s[t]  = ws[GEXP_OFF  + sbase + t];
      stab_s[t]  = ws[STAB_OFF  + sbase + t];
      decay_s[t] = ws[DECAY_OFF + sbase + t];
    }
    const float a_n = ws[A_OFF  + bh*NS_ + n];
    const float b_n = ws[BB_OFF + bh*NS_ + n];
    __syncthreads();
    // ---- P1: E + inter_C partial + pn partials
    float dqk = 0.f, ic = 0.f;
    {
      const float4* q4 = (const float4*)&q_s[c_t][0];
      const float4* k4 = (const float4*)&k_s[e_t][0];
      const float4* C4 = (const float4*)&C_s[e_t][0];
      #pragma unroll 4
      for (int d4=0; d4<32; d4++){
        float4 qv = q4[d4];
        dqk += dot4(qv, k4[d4]);
        ic  += dot4(qv, C4[d4]);
      }
    }
    float Ev = 0.f;
    if (e_t <= c_t)
      Ev = dqk * expf(lfacc_s[c_t] - lfacc_s[e_t] + ig_s[e_t] - stab_s[c_t]);
    E_s[c_t][e_t] = Ev;
    if (t < 128){
      int c2 = t>>3, j2 = t&7;
      float p = 0.f;
      #pragma unroll 4
      for (int dd=0; dd<16; dd++) p += q_s[c2][j2*16+dd]*n_s[j2*16+dd];
      pn_s[c2][j2] = p;
    }
    __syncthreads();
    // ---- P3: norm stats + h/U write
    {
      float rs = 0.f, pns = 0.f;
      #pragma unroll
      for (int cc=0;cc<16;cc++) rs += E_s[c_t][cc];
      #pragma unroll
      for (int j=0;j<8;j++) pns += pn_s[c_t][j];
      float tot = rs + decay_s[c_t]*pns;
      float hs = 0.f;
      #pragma unroll
      for (int cc=0;cc<16;cc++) hs += E_s[c_t][cc]*v_s[cc][e_t];
      float val = hs + decay_s[c_t]*ic;
      size_t oaddr = rowbase + (size_t)c_t*DIM_ + e0 + e_t;
      if (seg == 0){
        float nrm = fmaxf(fabsf(tot), expf(-stab_s[c_t])) + EPSv;
        out[oaddr] = val/nrm;
      } else {
        out[oaddr] = val;
        if (eh==0 && e_t==0) ws[SE_OFF + sbase + c_t] = tot;
      }
    }
    // ---- P4: kv + state update (C in LDS, n)
    {
      float kv[8] = {0,0,0,0,0,0,0,0};
      #pragma unroll
      for (int c=0;c<16;c++){
        float kc = k_s[c][d_t];
        #pragma unroll
        for (int j=0;j<8;j++) kv[j] += kc*vg_s[c][g_t*8+j];
      }
      #pragma unroll
      for (int j=0;j<8;j++){
        int e = g_t*8+j;
        C_s[e][d_t] = C_s[e][d_t]*a_n + kv[j]*b_n;
      }
      if (t < 128){
        float ks = 0.f;
        #pragma unroll
        for (int c=0;c<16;c++) ks += k_s[c][t]*gexp_s[c];
        n_s[t] = n_s[t]*a_n + ks*b_n;
      }
    }
  }
  __syncthreads();
  #pragma unroll
  for (int j=0;j<8;j++)
    ws[CEND_OFF + (size_t)bhseg*16384 + (size_t)(e0+g_t*8+j)*128 + d_t] = C_s[g_t*8+j][d_t];
  if (eh==0 && t<128) ws[NEND_OFF + bhseg*128 + t] = n_s[t];
}

// ---------------------------------------- K4: combine segment boundary states
__global__ __launch_bounds__(256) void k_comb(float* __restrict__ ws,
    float* __restrict__ Cl, float* __restrict__ nl){
  int gid = blockIdx.x*256 + threadIdx.x;
  if (gid < 32*16384){
    int bh = gid >> 14, elem = gid & 16383;
    size_t base = CEND_OFF + (size_t)bh*131072 + elem;
    float S = 0.f;
    #pragma unroll
    for (int j=1;j<8;j++){
      float E = ws[base + (size_t)(j-1)*16384];
      S = E + ws[DPF_OFF + bh*NSEG + (j-1)]*S;
      ws[base + (size_t)(j-1)*16384] = S;
    }
    float cl = ws[base + (size_t)7*16384] + ws[DPF_OFF + bh*NSEG + 7]*S;
    int e = elem>>7, d = elem&127;
    Cl[(size_t)bh*16384 + (size_t)d*128 + e] = cl;
  } else {
    int i = gid - 32*16384;
    if (i < 4096){
      int bh = i>>7, d = i&127;
      size_t base = NEND_OFF + bh*1024 + d;
      float S = 0.f;
      #pragma unroll
      for (int j=1;j<8;j++){
        float E = ws[base + (j-1)*128];
        S = E + ws[DPF_OFF + bh*NSEG + (j-1)]*S;
        ws[base + (j-1)*128] = S;
      }
      nl[bh*128+d] = ws[base + 7*128] + ws[DPF_OFF + bh*NSEG + 7]*S;
    }
  }
}

// -------------- K5: cross-segment correction + normalization, 256 thr, W=16
// grid 1792: eh = blk/224 (0..7), rem: bh = rem/7, seg = 1+rem%7
__global__ __launch_bounds__(256) void k_corr(const float* __restrict__ qg,
    float* __restrict__ ws, float* __restrict__ out){
  __shared__ __align__(16) float Cs[16][132];
  __shared__ __align__(16) float q_s[16][132];
  __shared__ float nst[128], pn_s[16][9];
  __shared__ float se_s[16], stb_s[16], dcy_s[16];
  const int blk = blockIdx.x;
  const int eh  = blk / 224;
  const int rem = blk % 224;
  const int bh  = rem / 7, seg = 1 + rem % 7;
  const int b = bh>>3, h = bh&7, e0 = eh*CS_;
  const int t = threadIdx.x, c_t = t>>4, e_t = t&15;
  size_t cbase = CEND_OFF + ((size_t)bh*NSEG + seg-1)*16384;
  #pragma unroll
  for (int i=0;i<2;i++){
    int f = i*256+t; int el = f>>5, d4 = f&31;
    ((float4*)&Cs[el][0])[d4] = *(const float4*)(ws + cbase + (size_t)(e0+el)*128 + 4*d4);
  }
  if (t<128) nst[t] = ws[NEND_OFF + (bh*NSEG+seg-1)*128 + t];

  for (int ci=0; ci<SEGC; ci++){
    const int n = seg*SEGC + ci;
    const size_t rowbase = ((size_t)b*S_ + (size_t)n*CS_)*DIM_ + (size_t)h*DH_;
    __syncthreads();
    #pragma unroll
    for (int i=0;i<2;i++){
      int f = i*256+t; int r = f>>5, d4 = f&31;
      float4 qv = *(const float4*)(qg + rowbase + (size_t)r*DIM_ + 4*d4);
      ((float4*)&q_s[r][0])[d4] = make_float4(qv.x*0.08838834764831845f,
          qv.y*0.08838834764831845f, qv.z*0.08838834764831845f, qv.w*0.08838834764831845f);
    }
    if (t < 16){
      size_t sr = (size_t)bh*S_ + n*CS_ + t;
      se_s[t] = ws[SE_OFF + sr]; stb_s[t] = ws[STAB_OFF + sr]; dcy_s[t] = ws[DECAY_OFF + sr];
    }
    const float dpn = ws[DP_OFF + bh*NS_ + n];
    __syncthreads();
    float corr = 0.f;
    {
      const float4* qq  = (const float4*)&q_s[c_t][0];
      const float4* cc4 = (const float4*)&Cs[e_t][0];
      #pragma unroll 4
      for (int d4=0; d4<32; d4++) corr += dot4(qq[d4], cc4[d4]);
    }
    if (t < 128){
      int c2 = t>>3, j2 = t&7;
      float p = 0.f;
      #pragma unroll 4
      for (int dd=0;dd<16;dd++) p += q_s[c2][j2*16+dd]*nst[j2*16+dd];
      pn_s[c2][j2] = p;
    }
    __syncthreads();
    {
      float pns = 0.f;
      #pragma unroll
      for (int j=0;j<8;j++) pns += pn_s[c_t][j];
      float dcp = dcy_s[c_t] * dpn;
      float denom = se_s[c_t] + dcp*pns;
      float nrm = fmaxf(fabsf(denom), expf(-stb_s[c_t])) + EPSv;
      size_t oaddr = rowbase + (size_t)c_t*DIM_ + e0 + e_t;
      out[oaddr] = (out[oaddr] + dcp*corr)/nrm;
    }
  }
}

// ------------------------------------------------------ K6: in-place LN
__global__ __launch_bounds__(256) void k_ln(float* __restrict__ out,
    const float* __restrict__ lnw, const float* __restrict__ lnb){
  int r = blockIdx.x*4 + (threadIdx.x>>6);
  int lane = threadIdx.x & 63;
  int b = r >> 14;
  int h = (r >> 11) & 7;
  int s = r & 2047;
  size_t base = ((size_t)b*S_ + s)*DIM_ + (size_t)h*DH_;
  float2 x = *(const float2*)&out[base + lane*2];
  float sm = x.x + x.y;
  #pragma unroll
  for (int off=32; off>0; off>>=1) sm += __shfl_xor(sm, off, 64);
  float mu = sm * (1.0f/128.0f);
  float d0 = x.x-mu, d1 = x.y-mu;
  float ss = d0*d0 + d1*d1;
  #pragma unroll
  for (int off=32; off>0; off>>=1) ss += __shfl_xor(ss, off, 64);
  float rstd = 1.0f/sqrtf(ss*(1.0f/128.0f) + LNEPS);
  int wi = h*DH_ + lane*2;
  float2 w2 = *(const float2*)&lnw[wi];
  float2 b2 = *(const float2*)&lnb[wi];
  float2 y;
  y.x = d0*rstd*(1.0f+w2.x) + b2.x;
  y.y = d1*rstd*(1.0f+w2.y) + b2.y;
  *(float2*)&out[base + lane*2] = y;
}

extern "C" void kernel_launch(void* const* d_in, const int* in_sizes, int n_in,
                              void* d_out, int out_size, void* d_ws, size_t ws_size,
                              hipStream_t stream){
  const float* q   = (const float*)d_in[0];
  const float* k   = (const float*)d_in[1];
  const float* v   = (const float*)d_in[2];
  const float* Wi  = (const float*)d_in[3];
  const float* bi  = (const float*)d_in[4];
  const float* Wf  = (const float*)d_in[5];
  const float* bf  = (const float*)d_in[6];
  const float* lnw = (const float*)d_in[7];
  const float* lnb = (const float*)d_in[8];
  float* out = (float*)d_out;                 // (B,S,DIM)
  float* Cl  = out + 8388608;                 // (B,NH,DH,DH)
  float* nl  = out + 8912896;                 // (B,NH,DH)
  float* ml  = out + 8916992;                 // (B,NH,1,1)
  float* ws  = (float*)d_ws;

  k_gates<<<512,  256, 0, stream>>>(q,k,v,Wi,bi,Wf,bf,ws);
  k_mid  <<<32,   256, 0, stream>>>(ws, ml);
  k_seg  <<<2048, 256, 0, stream>>>(q,k,v,ws,out);
  k_comb <<<2064, 256, 0, stream>>>(ws, Cl, nl);
  k_corr <<<1792, 256, 0, stream>>>(q, ws, out);
  k_ln   <<<16384,256, 0, stream>>>(out, lnw, lnb);
}